// Round 4
// baseline (202.498 us; speedup 1.0000x reference)
//
#include <hip/hip_runtime.h>
#include <hip/hip_bf16.h>
#include <stdint.h>

// Problem constants: T=512, B=32, I=512, H=512
#define T_DIM 512
#define B_DIM 32
#define K_DIM 512     // I
#define H_DIM 512
#define N_DIM 1536    // 3*H
#define M_DIM 16384   // T*B

typedef __bf16 bf16_t;
typedef bf16_t bf16x8 __attribute__((ext_vector_type(8)));
typedef float floatx4 __attribute__((ext_vector_type(4)));

#define LOG2E 1.442695041f     // 1/ln(2)
#define TWO_LOG2E 2.885390082f

// ---------- fp32 -> bf16 (RNE), 8 elems/thread, both inputs fused ----------
__device__ __forceinline__ unsigned int f2bf_bits(float f) {
  uint32_t u = __builtin_bit_cast(uint32_t, f);
  u += 0x7FFFu + ((u >> 16) & 1u);
  return u >> 16;
}

__global__ void convert_both_kernel(const float* __restrict__ x,
                                    unsigned short* __restrict__ xb,
                                    const float* __restrict__ W,
                                    unsigned short* __restrict__ Wb) {
  int bid = blockIdx.x;
  const float* in;
  unsigned short* out;
  int i;
  if (bid < 4096) {           // x: 8388608 elems = 4096 blocks
    in = x; out = xb; i = (bid * 256 + threadIdx.x) * 8;
  } else {                    // W_ih: 786432 elems = 384 blocks
    in = W; out = Wb; i = ((bid - 4096) * 256 + threadIdx.x) * 8;
  }
  const float4* p = (const float4*)(in + i);
  float4 f0 = p[0];
  float4 f1 = p[1];
  uint4 v;
  v.x = f2bf_bits(f0.x) | (f2bf_bits(f0.y) << 16);
  v.y = f2bf_bits(f0.z) | (f2bf_bits(f0.w) << 16);
  v.z = f2bf_bits(f1.x) | (f2bf_bits(f1.y) << 16);
  v.w = f2bf_bits(f1.z) | (f2bf_bits(f1.w) << 16);
  *(uint4*)(out + i) = v;
}

// ---------- bf16 GEMM: NT, 128x128 tile, BK=64, XOR-swizzled LDS ----------
// A: M x K bf16 (x), Bm: N x K bf16 (W_ih).
// Output written GATE-PACKED for the scan: C[m*1536 + h*3 + g], g in {r,z,n},
// pre-scaled (r,z by -log2e for sigmoid-via-exp2, n by +2*log2e for tanh).
__global__ __launch_bounds__(256) void gemm_bf16_kernel(
    const unsigned short* __restrict__ A, const unsigned short* __restrict__ Bm,
    float* __restrict__ C) {
  __shared__ bf16_t smem[16384];  // [0..8191] A-tile 128x64, [8192..] B-tile
  const int tid = threadIdx.x;
  const int lane = tid & 63;
  const int w = tid >> 6;
  const int tileM = blockIdx.x * 128;
  const int tileN = blockIdx.y * 128;
  const int waveM = w & 1;
  const int waveN = w >> 1;
  const int lm = lane & 15;
  const int lg = lane >> 4;       // 0..3 k-chunk group

  floatx4 acc[4][4] = {};

  for (int k0 = 0; k0 < K_DIM; k0 += 64) {
#pragma unroll
    for (int j = 0; j < 4; ++j) {
      // slot s in [0,1024): 16B chunks; row = s>>3, cpos = s&7
      int s = j * 256 + tid;
      int row = s >> 3;
      int cpos = s & 7;
      int kc = cpos ^ (row & 7);  // source chunk under swizzle
      bf16_t* la = smem + (j * 256 + w * 64) * 8;
      const unsigned short* ga = A + (size_t)(tileM + row) * K_DIM + k0 + kc * 8;
      __builtin_amdgcn_global_load_lds(
          (const __attribute__((address_space(1))) unsigned int*)ga,
          (__attribute__((address_space(3))) unsigned int*)la, 16, 0, 0);
      bf16_t* lb = smem + 8192 + (j * 256 + w * 64) * 8;
      const unsigned short* gb = Bm + (size_t)(tileN + row) * K_DIM + k0 + kc * 8;
      __builtin_amdgcn_global_load_lds(
          (const __attribute__((address_space(1))) unsigned int*)gb,
          (__attribute__((address_space(3))) unsigned int*)lb, 16, 0, 0);
    }
    __syncthreads();

#pragma unroll
    for (int ks = 0; ks < 2; ++ks) {
      bf16x8 af[4], bfg[4];
#pragma unroll
      for (int i = 0; i < 4; ++i) {
        int row = waveM * 64 + i * 16 + lm;
        int c = ks * 4 + lg;
        af[i] = *(const bf16x8*)(smem + row * 64 + (c ^ (row & 7)) * 8);
      }
#pragma unroll
      for (int j = 0; j < 4; ++j) {
        int row = waveN * 64 + j * 16 + lm;
        int c = ks * 4 + lg;
        bfg[j] = *(const bf16x8*)(smem + 8192 + row * 64 + (c ^ (row & 7)) * 8);
      }
#pragma unroll
      for (int i = 0; i < 4; ++i)
#pragma unroll
        for (int j = 0; j < 4; ++j)
          acc[i][j] = __builtin_amdgcn_mfma_f32_16x16x32_bf16(af[i], bfg[j],
                                                              acc[i][j], 0, 0, 0);
    }
    __syncthreads();
  }

  // Epilogue: C/D layout col=lane&15, row=(lane>>4)*4+reg (m89/m91 verified).
  // Gate-packed scatter: col -> (g = col>>9, h = col&511), addr m*1536 + h*3 + g.
  const int row0 = tileM + waveM * 64 + (lane >> 4) * 4;
  const int col0 = tileN + waveN * 64 + lm;
#pragma unroll
  for (int j = 0; j < 4; ++j) {
    const int col = col0 + j * 16;
    const int g = col >> 9;
    const int h = col & (H_DIM - 1);
    const float scl = (g == 2) ? TWO_LOG2E : -LOG2E;
#pragma unroll
    for (int i = 0; i < 4; ++i)
#pragma unroll
      for (int r = 0; r < 4; ++r)
        C[(size_t)(row0 + i * 16 + r) * N_DIM + h * 3 + g] = scl * acc[j < 100 ? i : i][j][r];
  }
}

// ---------- diagonal GRU scan ----------
// gx2 gate-packed: for m = t*B+b, the triple (gr',gz',gn') at
// gx2[m*1536 + h*3 .. +2], pre-scaled (gr',gz' by -log2e; gn' by 2*log2e).
// sigmoid(x) = rcp(1 + exp2(-log2e*x)); tanh(y) = 1 - 2*rcp(exp2(2*log2e*y)+1).
// Depth-16 register prefetch; per-step asm memory clobber pins the pipeline
// (R3 lesson: without it the compiler rotates the loads to just-in-time and
// the scan runs at one exposed memory round-trip per step).
__global__ __launch_bounds__(64) void indgru_scan_kernel(
    const float* __restrict__ gx, const float* __restrict__ h0,
    const float* __restrict__ w_hh, float* __restrict__ out,
    float* __restrict__ hlast) {
  const int idx = blockIdx.x * 64 + threadIdx.x;  // 0..16383
  const int b = idx >> 9;
  const int h = idx & (H_DIM - 1);
  const float wr = -LOG2E * w_hh[h];
  const float wz = -LOG2E * w_hh[H_DIM + h];
  const float wn = TWO_LOG2E * w_hh[2 * H_DIM + h];
  float hv = h0[idx];

  const float* base = gx + ((size_t)b * H_DIM + h) * 3;  // t-stride 49152 floats
  float* outp = out + (size_t)b * H_DIM + h;             // t-stride 16384 floats

  constexpr int D = 16;
  float pr[D], pz[D], pn[D];
#pragma unroll
  for (int t = 0; t < D; ++t) {
    const float* p = base + (size_t)t * (B_DIM * N_DIM);
    pr[t] = p[0];
    pz[t] = p[1];
    pn[t] = p[2];
  }

  for (int t0 = 0; t0 < T_DIM - D; t0 += D) {
#pragma unroll
    for (int s = 0; s < D; ++s) {
      const int t = t0 + s;
      float gr = pr[s], gz = pz[s], gn = pn[s];
      const float* p = base + (size_t)(t + D) * (B_DIM * N_DIM);
      pr[s] = p[0];
      pz[s] = p[1];
      pn[s] = p[2];
      asm volatile("" ::: "memory");  // pin prefetch distance
      float ar = fmaf(wr, hv, gr);
      float az = fmaf(wz, hv, gz);
      float t1 = wn * hv;
      float er = __builtin_amdgcn_exp2f(ar);
      float ez = __builtin_amdgcn_exp2f(az);
      float r = __builtin_amdgcn_rcpf(1.0f + er);
      float z = __builtin_amdgcn_rcpf(1.0f + ez);
      float en = __builtin_amdgcn_exp2f(fmaf(r, t1, gn));
      float u = __builtin_amdgcn_rcpf(1.0f + en);
      float n = fmaf(-2.0f, u, 1.0f);
      float zh = z * hv;
      float omz = 1.0f - z;
      hv = fmaf(n, omz, zh);
      outp[(size_t)t * (B_DIM * H_DIM)] = hv;
    }
  }
#pragma unroll
  for (int s = 0; s < D; ++s) {
    const int t = T_DIM - D + s;
    float ar = fmaf(wr, hv, pr[s]);
    float az = fmaf(wz, hv, pz[s]);
    float t1 = wn * hv;
    float er = __builtin_amdgcn_exp2f(ar);
    float ez = __builtin_amdgcn_exp2f(az);
    float r = __builtin_amdgcn_rcpf(1.0f + er);
    float z = __builtin_amdgcn_rcpf(1.0f + ez);
    float en = __builtin_amdgcn_exp2f(fmaf(r, t1, pn[s]));
    float u = __builtin_amdgcn_rcpf(1.0f + en);
    float n = fmaf(-2.0f, u, 1.0f);
    float zh = z * hv;
    float omz = 1.0f - z;
    hv = fmaf(n, omz, zh);
    outp[(size_t)t * (B_DIM * H_DIM)] = hv;
  }
  hlast[idx] = hv;
}

extern "C" void kernel_launch(void* const* d_in, const int* in_sizes, int n_in,
                              void* d_out, int out_size, void* d_ws, size_t ws_size,
                              hipStream_t stream) {
  const float* x    = (const float*)d_in[0];   // (T,B,I)  = 8388608
  const float* h0   = (const float*)d_in[1];   // (B,H)    = 16384
  const float* W_ih = (const float*)d_in[2];   // (3H,I)   = 786432
  const float* w_hh = (const float*)d_in[3];   // (3,H)    = 1536

  float* out = (float*)d_out;                          // (T,B,H)
  float* hlast = out + (size_t)T_DIM * B_DIM * H_DIM;  // (1,B,H)

  // workspace layout: xb(bf16) 16 MB | Wb(bf16) 1.5 MB | gx2(fp32) 100 MB
  char* ws = (char*)d_ws;
  unsigned short* xb = (unsigned short*)ws;
  unsigned short* Wb = (unsigned short*)(ws + 16777216);
  float* gx = (float*)(ws + 16777216 + 1572864);

  convert_both_kernel<<<4480, 256, 0, stream>>>(x, xb, W_ih, Wb);

  dim3 grid(M_DIM / 128, N_DIM / 128);  // 128 x 12
  gemm_bf16_kernel<<<grid, 256, 0, stream>>>(xb, Wb, gx);

  indgru_scan_kernel<<<256, 64, 0, stream>>>(gx, h0, w_hh, out, hlast);
}

// Round 5
// 163.137 us; speedup vs baseline: 1.2413x; 1.2413x over previous
//
#include <hip/hip_runtime.h>
#include <hip/hip_bf16.h>
#include <stdint.h>

// Problem constants: T=512, B=32, I=512, H=512
#define T_DIM 512
#define B_DIM 32
#define K_DIM 512     // I
#define H_DIM 512
#define N_DIM 1536    // 3*H
#define M_DIM 16384   // T*B

typedef __bf16 bf16_t;
typedef bf16_t bf16x8 __attribute__((ext_vector_type(8)));
typedef float floatx4 __attribute__((ext_vector_type(4)));

#define LOG2E 1.442695041f     // 1/ln(2)
#define TWO_LOG2E 2.885390082f

// ---------- fp32 -> bf16 (RNE), 8 elems/thread, both inputs fused ----------
// W_ih rows are PERMUTED on the fly: packed row h*3+g <- original row g*512+h.
// This makes the GEMM's N axis natively gate-packed, so the GEMM epilogue
// writes full 64B lines (R4 lesson: stride-12B scatter tripled WRITE_SIZE
// via partial-line RMW at HBM).
__device__ __forceinline__ unsigned int f2bf_bits(float f) {
  uint32_t u = __builtin_bit_cast(uint32_t, f);
  u += 0x7FFFu + ((u >> 16) & 1u);
  return u >> 16;
}

__global__ void convert_both_kernel(const float* __restrict__ x,
                                    unsigned short* __restrict__ xb,
                                    const float* __restrict__ W,
                                    unsigned short* __restrict__ Wb) {
  int bid = blockIdx.x;
  int i;
  const float* in;
  unsigned short* out;
  if (bid < 4096) {           // x: 8388608 elems = 4096 blocks, identity
    in = x; out = xb;
    i = (bid * 256 + threadIdx.x) * 8;
  } else {                    // W_ih: 786432 elems = 384 blocks, row-permuted
    i = ((bid - 4096) * 256 + threadIdx.x) * 8;
    int rw = i >> 9;          // original row (g*512+h), K=512 elems/row
    int k = i & 511;
    int g = rw >> 9;
    int h = rw & (H_DIM - 1);
    in = W;
    out = Wb + ((h * 3 + g) << 9) + k - i;  // so out+i hits permuted slot
  }
  const float4* p = (const float4*)(in + i);
  float4 f0 = p[0];
  float4 f1 = p[1];
  uint4 v;
  v.x = f2bf_bits(f0.x) | (f2bf_bits(f0.y) << 16);
  v.y = f2bf_bits(f0.z) | (f2bf_bits(f0.w) << 16);
  v.z = f2bf_bits(f1.x) | (f2bf_bits(f1.y) << 16);
  v.w = f2bf_bits(f1.z) | (f2bf_bits(f1.w) << 16);
  *(uint4*)(out + i) = v;
}

// ---------- bf16 GEMM: NT, 128x128 tile, BK=64, XOR-swizzled LDS ----------
// A: M x K bf16 (x), Bm: N x K bf16 (W_ih, rows gate-packed h*3+g).
// C row-major M x N fp32 — since N is packed, C[m][h*3+g] directly.
// Pre-scales: gate r,z (n%3<2) by -log2e (sigmoid via exp2), gate n by
// +2*log2e (tanh via exp2).
__global__ __launch_bounds__(256) void gemm_bf16_kernel(
    const unsigned short* __restrict__ A, const unsigned short* __restrict__ Bm,
    float* __restrict__ C) {
  __shared__ bf16_t smem[16384];  // [0..8191] A-tile 128x64, [8192..] B-tile
  const int tid = threadIdx.x;
  const int lane = tid & 63;
  const int w = tid >> 6;
  const int tileM = blockIdx.x * 128;
  const int tileN = blockIdx.y * 128;
  const int waveM = w & 1;
  const int waveN = w >> 1;
  const int lm = lane & 15;
  const int lg = lane >> 4;       // 0..3 k-chunk group

  floatx4 acc[4][4] = {};

  for (int k0 = 0; k0 < K_DIM; k0 += 64) {
#pragma unroll
    for (int j = 0; j < 4; ++j) {
      // slot s in [0,1024): 16B chunks; row = s>>3, cpos = s&7
      int s = j * 256 + tid;
      int row = s >> 3;
      int cpos = s & 7;
      int kc = cpos ^ (row & 7);  // source chunk under swizzle
      bf16_t* la = smem + (j * 256 + w * 64) * 8;
      const unsigned short* ga = A + (size_t)(tileM + row) * K_DIM + k0 + kc * 8;
      __builtin_amdgcn_global_load_lds(
          (const __attribute__((address_space(1))) unsigned int*)ga,
          (__attribute__((address_space(3))) unsigned int*)la, 16, 0, 0);
      bf16_t* lb = smem + 8192 + (j * 256 + w * 64) * 8;
      const unsigned short* gb = Bm + (size_t)(tileN + row) * K_DIM + k0 + kc * 8;
      __builtin_amdgcn_global_load_lds(
          (const __attribute__((address_space(1))) unsigned int*)gb,
          (__attribute__((address_space(3))) unsigned int*)lb, 16, 0, 0);
    }
    __syncthreads();

#pragma unroll
    for (int ks = 0; ks < 2; ++ks) {
      bf16x8 af[4], bfg[4];
#pragma unroll
      for (int i = 0; i < 4; ++i) {
        int row = waveM * 64 + i * 16 + lm;
        int c = ks * 4 + lg;
        af[i] = *(const bf16x8*)(smem + row * 64 + (c ^ (row & 7)) * 8);
      }
#pragma unroll
      for (int j = 0; j < 4; ++j) {
        int row = waveN * 64 + j * 16 + lm;
        int c = ks * 4 + lg;
        bfg[j] = *(const bf16x8*)(smem + 8192 + row * 64 + (c ^ (row & 7)) * 8);
      }
#pragma unroll
      for (int i = 0; i < 4; ++i)
#pragma unroll
        for (int j = 0; j < 4; ++j)
          acc[i][j] = __builtin_amdgcn_mfma_f32_16x16x32_bf16(af[i], bfg[j],
                                                              acc[i][j], 0, 0, 0);
    }
    __syncthreads();
  }

  // Epilogue: C/D layout col=lane&15, row=(lane>>4)*4+reg (m89/m91 verified).
  // 16 consecutive lanes write 16 consecutive floats -> full 64B lines.
  const int row0 = tileM + waveM * 64 + (lane >> 4) * 4;
  const int col0 = tileN + waveN * 64 + lm;
#pragma unroll
  for (int j = 0; j < 4; ++j) {
    const int col = col0 + j * 16;
    const float scl = (col % 3 == 2) ? TWO_LOG2E : -LOG2E;
#pragma unroll
    for (int i = 0; i < 4; ++i)
#pragma unroll
      for (int r = 0; r < 4; ++r)
        C[(size_t)(row0 + i * 16 + r) * N_DIM + col] = scl * acc[i][j][r];
  }
}

// ---------- diagonal GRU scan ----------
// gx gate-packed: triple (gr',gz',gn') at gx[m*1536 + h*3 .. +2], pre-scaled
// (gr',gz' by -log2e; gn' by 2*log2e). One dwordx3 load per step per thread.
// sigmoid(x) = rcp(1 + exp2(-log2e*x)); tanh(y) = 1 - 2*rcp(exp2(2*log2e*y)+1).
// Depth-16 register prefetch; per-step asm memory clobber pins the distance
// (R3 lesson: otherwise the compiler rotates loads to just-in-time and the
// scan runs at one exposed memory round-trip per step).
__global__ __launch_bounds__(64) void indgru_scan_kernel(
    const float* __restrict__ gx, const float* __restrict__ h0,
    const float* __restrict__ w_hh, float* __restrict__ out,
    float* __restrict__ hlast) {
  const int idx = blockIdx.x * 64 + threadIdx.x;  // 0..16383
  const int b = idx >> 9;
  const int h = idx & (H_DIM - 1);
  const float wr = -LOG2E * w_hh[h];
  const float wz = -LOG2E * w_hh[H_DIM + h];
  const float wn = TWO_LOG2E * w_hh[2 * H_DIM + h];
  float hv = h0[idx];

  const float* base = gx + ((size_t)b * H_DIM + h) * 3;  // t-stride 49152 floats
  float* outp = out + (size_t)b * H_DIM + h;             // t-stride 16384 floats

  constexpr int D = 16;
  float pr[D], pz[D], pn[D];
#pragma unroll
  for (int t = 0; t < D; ++t) {
    const float* p = base + (size_t)t * (B_DIM * N_DIM);
    pr[t] = p[0];
    pz[t] = p[1];
    pn[t] = p[2];
  }

  for (int t0 = 0; t0 < T_DIM - D; t0 += D) {
#pragma unroll
    for (int s = 0; s < D; ++s) {
      const int t = t0 + s;
      float gr = pr[s], gz = pz[s], gn = pn[s];
      const float* p = base + (size_t)(t + D) * (B_DIM * N_DIM);
      pr[s] = p[0];
      pz[s] = p[1];
      pn[s] = p[2];
      asm volatile("" ::: "memory");  // pin prefetch distance
      float ar = fmaf(wr, hv, gr);
      float az = fmaf(wz, hv, gz);
      float t1 = wn * hv;
      float er = __builtin_amdgcn_exp2f(ar);
      float ez = __builtin_amdgcn_exp2f(az);
      float r = __builtin_amdgcn_rcpf(1.0f + er);
      float z = __builtin_amdgcn_rcpf(1.0f + ez);
      float en = __builtin_amdgcn_exp2f(fmaf(r, t1, gn));
      float u = __builtin_amdgcn_rcpf(1.0f + en);
      float n = fmaf(-2.0f, u, 1.0f);
      float zh = z * hv;
      float omz = 1.0f - z;
      hv = fmaf(n, omz, zh);
      outp[(size_t)t * (B_DIM * H_DIM)] = hv;
    }
  }
#pragma unroll
  for (int s = 0; s < D; ++s) {
    const int t = T_DIM - D + s;
    float ar = fmaf(wr, hv, pr[s]);
    float az = fmaf(wz, hv, pz[s]);
    float t1 = wn * hv;
    float er = __builtin_amdgcn_exp2f(ar);
    float ez = __builtin_amdgcn_exp2f(az);
    float r = __builtin_amdgcn_rcpf(1.0f + er);
    float z = __builtin_amdgcn_rcpf(1.0f + ez);
    float en = __builtin_amdgcn_exp2f(fmaf(r, t1, pn[s]));
    float u = __builtin_amdgcn_rcpf(1.0f + en);
    float n = fmaf(-2.0f, u, 1.0f);
    float zh = z * hv;
    float omz = 1.0f - z;
    hv = fmaf(n, omz, zh);
    outp[(size_t)t * (B_DIM * H_DIM)] = hv;
  }
  hlast[idx] = hv;
}

extern "C" void kernel_launch(void* const* d_in, const int* in_sizes, int n_in,
                              void* d_out, int out_size, void* d_ws, size_t ws_size,
                              hipStream_t stream) {
  const float* x    = (const float*)d_in[0];   // (T,B,I)  = 8388608
  const float* h0   = (const float*)d_in[1];   // (B,H)    = 16384
  const float* W_ih = (const float*)d_in[2];   // (3H,I)   = 786432
  const float* w_hh = (const float*)d_in[3];   // (3,H)    = 1536

  float* out = (float*)d_out;                          // (T,B,H)
  float* hlast = out + (size_t)T_DIM * B_DIM * H_DIM;  // (1,B,H)

  // workspace layout: xb(bf16) 16 MB | Wb(bf16, row-packed) 1.5 MB | gx(fp32) 100 MB
  char* ws = (char*)d_ws;
  unsigned short* xb = (unsigned short*)ws;
  unsigned short* Wb = (unsigned short*)(ws + 16777216);
  float* gx = (float*)(ws + 16777216 + 1572864);

  convert_both_kernel<<<4480, 256, 0, stream>>>(x, xb, W_ih, Wb);

  dim3 grid(M_DIM / 128, N_DIM / 128);  // 128 x 12
  gemm_bf16_kernel<<<grid, 256, 0, stream>>>(xb, Wb, gx);

  indgru_scan_kernel<<<256, 64, 0, stream>>>(gx, h0, w_hh, out, hlast);
}